// Round 1
// 1055.086 us; speedup vs baseline: 1.0599x; 1.0599x over previous
//
#include <hip/hip_runtime.h>

// ---------------------------------------------------------------------------
// GLA_GCN bf16-MFMA pipeline. B=4096, J=25, D_IN=512, D_H=256, D_OUT=512.
// Partition 1 is dead (all its joints overwritten by parts 2/3/4).
// GEMM: 256x256 tile, BK=32, 8 waves, 4-deep LDS ring + counted vmcnt
// (never 0 in main loop), 1 barrier/K-step, XOR-swizzled LDS (conflict-free
// ds_read_b128), setprio around MFMA, bijective XCD block swizzle.
// XG|XL stored interleaved per row (XGL, lda=1024) so fusion GEMM is plain.
// ---------------------------------------------------------------------------

#define BATCH 4096
#define NJOINT 25
#define MROWS (BATCH * NJOINT)          // 102400
#define SZ_FULL (MROWS * 512)           // 52,428,800 bf16 elements

typedef __attribute__((ext_vector_type(8))) short short8;
typedef __attribute__((ext_vector_type(4))) float float4_;

__device__ __forceinline__ float b2f(ushort u) {
    union { float f; uint32_t i; } x; x.i = ((uint32_t)u) << 16; return x.f;
}
__device__ __forceinline__ ushort f2b(float f) {
    union { float f; uint32_t i; } x; x.f = f;
    uint32_t r = x.i + 0x7fff + ((x.i >> 16) & 1);
    return (ushort)(r >> 16);
}
__device__ __forceinline__ void async16(const void* g, void* l) {
    __builtin_amdgcn_global_load_lds(
        (const __attribute__((address_space(1))) void*)g,
        (__attribute__((address_space(3))) void*)l, 16, 0, 0);
}

// ---------------------------------------------------------------------------
// Adjacency normalization (fp32, tiny)
// ---------------------------------------------------------------------------
__device__ void norm_one(const float* A, int n, float* out, float* sAdj, float* sD) {
    int t = threadIdx.x;
    for (int i = t; i < n * n; i += 256) sAdj[i] = A[i];
    __syncthreads();
    if (t < n) {
        float s = 0.f;
        for (int j = 0; j < n; j++) s += sAdj[t * n + j];
        sD[t] = 1.0f / sqrtf(fmaxf(s, 1e-6f));
    }
    __syncthreads();
    for (int i = t; i < n * n; i += 256) {
        int r = i / n, c = i % n;
        out[i] = sD[r] * sAdj[i] * sD[c];
    }
    __syncthreads();
}

__global__ __launch_bounds__(256) void adjnorm_kernel(
    const float* Ag, const float* A0, const float* A2, const float* A3,
    const float* A4, float* ADJ) {
    __shared__ float sAdj[640];
    __shared__ float sD[32];
    norm_one(Ag, 25, ADJ, sAdj, sD);
    norm_one(A0, 5, ADJ + 640 + 0 * 64, sAdj, sD);
    norm_one(A2, 3, ADJ + 640 + 1 * 64, sAdj, sD);
    norm_one(A3, 3, ADJ + 640 + 2 * 64, sAdj, sD);
    norm_one(A4, 6, ADJ + 640 + 3 * 64, sAdj, sD);
}

// ---------------------------------------------------------------------------
// fp32 -> bf16 convert (x), float4 -> ushort4
// ---------------------------------------------------------------------------
__global__ __launch_bounds__(256) void cvt_bf16(const float* __restrict__ in,
                                                ushort* __restrict__ out, int n4) {
    int id = blockIdx.x * 256 + threadIdx.x;
    if (id < n4) {
        float4 v = ((const float4*)in)[id];
        ushort4 o;
        o.x = f2b(v.x); o.y = f2b(v.y); o.z = f2b(v.z); o.w = f2b(v.w);
        ((ushort4*)out)[id] = o;
    }
}

// ---------------------------------------------------------------------------
// Weight transpose + convert: W fp32 [K][N] -> Wt bf16 [N][K]. K,N mult of 32.
// ---------------------------------------------------------------------------
__global__ __launch_bounds__(256) void wtrans(const float* __restrict__ W,
                                              ushort* __restrict__ Wt, int K, int N) {
    __shared__ float tile[32][33];
    int t = threadIdx.x;
    int tx = t & 31, ty = t >> 5;  // ty 0..7
    int k0 = blockIdx.y * 32, n0 = blockIdx.x * 32;
    for (int r = ty; r < 32; r += 8)
        tile[r][tx] = W[(size_t)(k0 + r) * N + n0 + tx];
    __syncthreads();
    for (int r = ty; r < 32; r += 8)
        Wt[(size_t)(n0 + r) * K + k0 + tx] = f2b(tile[tx][r]);
}

// ---------------------------------------------------------------------------
// Zero XL joints 17..24 in XGL interleaved layout (row stride 1024, XL at +512)
// ---------------------------------------------------------------------------
__global__ __launch_bounds__(256) void zero_tail(ushort* __restrict__ XGL) {
    int id = blockIdx.x * 256 + threadIdx.x;   // 4,194,304 ushort4 writes
    int f4 = id & 127;
    int rj = (id >> 7) & 7;
    int b = id >> 10;
    ushort4 z; z.x = 0; z.y = 0; z.z = 0; z.w = 0;
    ((ushort4*)(XGL + ((size_t)(b * 25 + 17 + rj) * 1024 + 512)))[f4] = z;
}

// ---------------------------------------------------------------------------
// bf16 MFMA GEMM: C[M,N] = act(A @ Wt^T + bias)
//   A: bf16 row-major (lda), Wt: bf16 [N][K] pre-transposed, C: ldc stride.
//   256x256 tile, BK=32, 8 waves (2M x 4N), each 128x64 via 8x4 of
//   mfma_f32_16x16x32_bf16. LDS: 4-buffer ring of (A 8192 + B 8192) ushorts
//   = 128 KiB. Prefetch distance 2, s_waitcnt vmcnt(8) steady-state, one
//   s_barrier per K-step. LDS 16B-slot XOR swizzle: slot ^= (row>>1)&3,
//   applied on the global source at stage time and on the ds_read address.
//   GATHER: A row m -> Xb row (m/gn)*25 + idx[m%gn] (staging only).
// ---------------------------------------------------------------------------
template <bool GATHER, bool BIAS, bool RELU, bool OUTF32>
__global__ __launch_bounds__(512, 2) void gemm256(
    const ushort* __restrict__ A, const ushort* __restrict__ Wt,
    const float* __restrict__ bias, void* __restrict__ C,
    int M, int N, int K, int lda, int ldc,
    int gn, int g0, int g1, int g2, int g3, int g4, int g5) {
    __shared__ ushort lds[65536];   // 4 x (A[256][32] + B[256][32]) = 128 KiB
    int t = threadIdx.x;
    int l = t & 63, w = t >> 6;

    // bijective XCD swizzle (all grids are multiples of 8); N-tile fastest
    int nwg = (int)gridDim.x;
    int cpx = nwg >> 3;
    int wg = ((int)blockIdx.x & 7) * cpx + ((int)blockIdx.x >> 3);
    int gx = N >> 8;
    int tm = wg / gx, tn = wg - tm * gx;
    int bm = tm << 8, bn = tn << 8;

    // ---- staging roles: lane l covers row (l>>2), 16B slot (l&3); wave w
    //      stages rows w*16..+16 (issue 0) and 128+w*16..+16 (issue 1) ----
    int rA0 = (w << 4) + (l >> 2);         // 0..127
    int rA1 = 128 + rA0;                   // 128..255
    int qp = l & 3;
    int qA0 = qp ^ ((rA0 >> 1) & 3);
    int qA1 = qp ^ ((rA1 >> 1) & 3);
    int grA0 = bm + rA0, grA1 = bm + rA1;
    if (GATHER) {
        int map[6] = {g0, g1, g2, g3, g4, g5};
        int b0 = grA0 / gn; grA0 = b0 * 25 + map[grA0 - b0 * gn];
        int b1 = grA1 / gn; grA1 = b1 * 25 + map[grA1 - b1 * gn];
    }
    const ushort* pA0 = A + (size_t)grA0 * lda + (qA0 << 3);
    const ushort* pA1 = A + (size_t)grA1 * lda + (qA1 << 3);
    const ushort* pB0 = Wt + (size_t)(bn + rA0) * K + (qA0 << 3);
    const ushort* pB1 = Wt + (size_t)(bn + rA1) * K + (qA1 << 3);
    int sA0 = w << 9;                      // (0*8+w)*512 ushorts
    int sA1 = (8 + w) << 9;                // (1*8+w)*512

    // ---- fragment read offsets (ushort index within one ring buffer) ----
    int wm = w >> 2, wn = w & 3;           // 2 x 4 wave grid
    int lr = l & 15, q = l >> 4;
    int aoff[8], boff[4];
#pragma unroll
    for (int fi = 0; fi < 8; fi++) {
        int r = (wm << 7) + (fi << 4) + lr;
        aoff[fi] = (r << 5) + ((q ^ ((r >> 1) & 3)) << 3);
    }
#pragma unroll
    for (int fj = 0; fj < 4; fj++) {
        int r = (wn << 6) + (fj << 4) + lr;
        boff[fj] = 8192 + (r << 5) + ((q ^ ((r >> 1) & 3)) << 3);
    }

    float4_ acc[8][4];
#pragma unroll
    for (int fi = 0; fi < 8; fi++)
#pragma unroll
        for (int fj = 0; fj < 4; fj++) acc[fi][fj] = (float4_)0.f;

    int NT = K >> 5;

#define STAGE(kt_) do {                                      \
        int bo_ = ((kt_) & 3) << 14;                         \
        int ko_ = (kt_) << 5;                                \
        async16(pA0 + ko_, &lds[bo_ + sA0]);                 \
        async16(pA1 + ko_, &lds[bo_ + sA1]);                 \
        async16(pB0 + ko_, &lds[bo_ + 8192 + sA0]);          \
        async16(pB1 + ko_, &lds[bo_ + 8192 + sA1]);          \
    } while (0)

    STAGE(0);
    STAGE(1);
    for (int kt = 0; kt < NT; ++kt) {
        if (kt + 2 < NT) {
            STAGE(kt + 2);
            asm volatile("s_waitcnt vmcnt(8)" ::: "memory");  // tile kt landed
        } else if (kt + 1 < NT) {
            asm volatile("s_waitcnt vmcnt(4)" ::: "memory");
        } else {
            asm volatile("s_waitcnt vmcnt(0)" ::: "memory");
        }
        __builtin_amdgcn_s_barrier();          // everyone's tile-kt landed
        __builtin_amdgcn_sched_barrier(0);     // keep reads below the barrier
        int bo = (kt & 3) << 14;
        short8 af[8], bf[4];
#pragma unroll
        for (int fj = 0; fj < 4; fj++) bf[fj] = *(const short8*)&lds[bo + boff[fj]];
#pragma unroll
        for (int fi = 0; fi < 8; fi++) af[fi] = *(const short8*)&lds[bo + aoff[fi]];
        __builtin_amdgcn_s_setprio(1);
#pragma unroll
        for (int fi = 0; fi < 8; fi++)
#pragma unroll
            for (int fj = 0; fj < 4; fj++)
                acc[fi][fj] = __builtin_amdgcn_mfma_f32_16x16x32_bf16(
                    af[fi], bf[fj], acc[fi][fj], 0, 0, 0);
        __builtin_amdgcn_s_setprio(0);
    }
#undef STAGE

    // epilogue: C/D layout col=lane&15, row=(lane>>4)*4+reg
    int cl = lr;
    float bv[4];
#pragma unroll
    for (int fj = 0; fj < 4; fj++)
        bv[fj] = BIAS ? bias[bn + (wn << 6) + (fj << 4) + cl] : 0.f;
#pragma unroll
    for (int fi = 0; fi < 8; fi++) {
        int row0 = bm + (wm << 7) + (fi << 4) + (q << 2);
#pragma unroll
        for (int r = 0; r < 4; r++) {
            size_t rowoff = (size_t)(row0 + r) * ldc;
#pragma unroll
            for (int fj = 0; fj < 4; fj++) {
                int col = bn + (wn << 6) + (fj << 4) + cl;
                float v = acc[fi][fj][r] + bv[fj];
                if (RELU) v = fmaxf(v, 0.f);
                if (OUTF32)
                    ((float*)C)[rowoff + col] = v;
                else
                    ((ushort*)C)[rowoff + col] = f2b(v);
            }
        }
    }
    (void)M;
}

// ---------------------------------------------------------------------------
// In-place joint mix on bf16 tensor with row stride ldr:
//   T[b,i,f] = relu(sum_j adj[i,j]*T[b,j,f] + bias[f])
// ---------------------------------------------------------------------------
template <int NJ>
__global__ __launch_bounds__(256) void mix_inplace(
    ushort* __restrict__ T, const float* __restrict__ adjn,
    const float* __restrict__ bias, int F, int ldr) {
    __shared__ float As[NJ * NJ];
    int t = threadIdx.x;
    for (int i = t; i < NJ * NJ; i += 256) As[i] = adjn[i];
    __syncthreads();
    int id = blockIdx.x * 256 + t;
    int f = id % F;
    int b = id / F;
    ushort* base = T + (size_t)(b * NJ) * ldr + f;
    float v[NJ];
#pragma unroll
    for (int j = 0; j < NJ; j++) v[j] = b2f(base[(size_t)j * ldr]);
    float bi = bias[f];
#pragma unroll
    for (int i = 0; i < NJ; i++) {
        float o = 0.f;
#pragma unroll
        for (int j = 0; j < NJ; j++) o += As[i * NJ + j] * v[j];
        base[(size_t)i * ldr] = f2b(fmaxf(o + bi, 0.f));
    }
}

// ---------------------------------------------------------------------------
// Local layer-b mix + scatter into XL half of XGL (row stride 1024), bf16
// ---------------------------------------------------------------------------
template <int NJ>
__global__ __launch_bounds__(256) void mix_scatter(
    const ushort* __restrict__ P, const float* __restrict__ adjn,
    const float* __restrict__ bias, ushort* __restrict__ XL,
    int j0, int j1, int j2, int j3, int j4, int j5) {
    __shared__ float As[NJ * NJ];
    __shared__ int jm[NJ];
    int t = threadIdx.x;
    for (int i = t; i < NJ * NJ; i += 256) As[i] = adjn[i];
    if (t == 0) {
        int tmp[6] = {j0, j1, j2, j3, j4, j5};
        for (int i = 0; i < NJ; i++) jm[i] = tmp[i];
    }
    __syncthreads();
    int id = blockIdx.x * 256 + t;
    int f = id & 511;
    int b = id >> 9;
    float v[NJ];
    const ushort* base = P + (size_t)(b * NJ) * 512 + f;
#pragma unroll
    for (int j = 0; j < NJ; j++) v[j] = b2f(base[(size_t)j * 512]);
    float bi = bias[f];
#pragma unroll
    for (int i = 0; i < NJ; i++) {
        float o = 0.f;
#pragma unroll
        for (int j = 0; j < NJ; j++) o += As[i * NJ + j] * v[j];
        XL[((size_t)(b * 25 + jm[i])) * 1024 + f] = f2b(fmaxf(o + bi, 0.f));
    }
}

// ---------------------------------------------------------------------------
extern "C" void kernel_launch(void* const* d_in, const int* in_sizes, int n_in,
                              void* d_out, int out_size, void* d_ws,
                              size_t ws_size, hipStream_t stream) {
    const float* x    = (const float*)d_in[0];
    const float* adjg = (const float*)d_in[1];
    const float* al0  = (const float*)d_in[2];
    const float* al2  = (const float*)d_in[4];
    const float* al3  = (const float*)d_in[5];
    const float* al4  = (const float*)d_in[6];
    const float* Wg0  = (const float*)d_in[7];
    const float* bg0  = (const float*)d_in[8];
    const float* Wg1  = (const float*)d_in[9];
    const float* bg1  = (const float*)d_in[10];
    const float* Wf0  = (const float*)d_in[31];
    const float* bf0  = (const float*)d_in[32];
    const float* Wf1  = (const float*)d_in[33];
    const float* bf1  = (const float*)d_in[34];

    float* ws = (float*)d_ws;
    float* ADJ = ws;                          // 4096 floats
    ushort* U  = (ushort*)(ws + 4096);
    ushort* Xb  = U;                          // (B*25,512) bf16; HF reuses this
    ushort* XGL = U + (size_t)SZ_FULL;        // (B*25,1024): [XG | XL] per row
    ushort* S   = XGL + (size_t)MROWS * 1024; // 26.2M ushorts scratch
    ushort* T  = S;                           // (B*25,256)
    ushort* P1 = S;                           // (B*n,256) <= 6.3M
    ushort* P3 = S + 6291456;                 // (B*n,512) <= 12.6M
    ushort* Wb = S + 26214400;                // 2.1M ushorts of weights
    ushort* HF = Xb;                          // fusion hidden, reuses Xb

    ushort* Wg0t = Wb;                        // [256][512]
    ushort* Wg1t = Wb + 131072;               // [512][256]
    ushort* Wf0t = Wb + 1310720;              // [512][1024]
    ushort* Wf1t = Wb + 1835008;              // [512][512]

    dim3 blk(256);
    dim3 blk512(512);

    adjnorm_kernel<<<1, blk, 0, stream>>>(adjg, al0, al2, al3, al4, ADJ);
    cvt_bf16<<<SZ_FULL / 4 / 256, blk, 0, stream>>>(x, Xb, SZ_FULL / 4);
    zero_tail<<<16384, blk, 0, stream>>>(XGL);

    wtrans<<<dim3(256 / 32, 512 / 32), blk, 0, stream>>>(Wg0, Wg0t, 512, 256);
    wtrans<<<dim3(512 / 32, 256 / 32), blk, 0, stream>>>(Wg1, Wg1t, 256, 512);
    wtrans<<<dim3(512 / 32, 1024 / 32), blk, 0, stream>>>(Wf0, Wf0t, 1024, 512);
    wtrans<<<dim3(512 / 32, 512 / 32), blk, 0, stream>>>(Wf1, Wf1t, 512, 512);

    struct Part { int n, widx; int idx[6]; };
    const Part parts[4] = {
        {5, 11, {0, 1, 2, 3, 4, 0}},
        {3, 19, {5, 7, 9, 0, 0, 0}},
        {3, 23, {6, 8, 10, 0, 0, 0}},
        {6, 27, {11, 12, 13, 14, 15, 16}},
    };
    for (int q = 0; q < 4; q++) {
        ushort* Wat = Wb + 262144 + q * 262144;
        ushort* Wbt = Wat + 131072;
        wtrans<<<dim3(8, 16), blk, 0, stream>>>((const float*)d_in[parts[q].widx], Wat, 512, 256);
        wtrans<<<dim3(16, 8), blk, 0, stream>>>((const float*)d_in[parts[q].widx + 2], Wbt, 256, 512);
    }

    // global branch: XG written into even half of XGL (ldc=1024)
    gemm256<false, false, false, false><<<400, blk512, 0, stream>>>(
        Xb, Wg0t, nullptr, T, MROWS, 256, 512, 512, 256, 0, 0, 0, 0, 0, 0, 0);
    mix_inplace<25><<<BATCH * 256 / 256, blk, 0, stream>>>(T, ADJ, bg0, 256, 256);
    gemm256<false, false, false, false><<<800, blk512, 0, stream>>>(
        T, Wg1t, nullptr, XGL, MROWS, 512, 256, 256, 1024, 0, 0, 0, 0, 0, 0, 0);
    mix_inplace<25><<<BATCH * 512 / 256, blk, 0, stream>>>(XGL, ADJ, bg1, 512, 1024);

    // local branch (parts 0,2,3,4); XL written into odd half of XGL
    const int slots[4] = {0, 1, 2, 3};
    for (int q = 0; q < 4; q++) {
        const Part& P = parts[q];
        const float* ba = (const float*)d_in[P.widx + 1];
        const float* bb = (const float*)d_in[P.widx + 3];
        ushort* Wat = Wb + 262144 + q * 262144;
        ushort* Wbt = Wat + 131072;
        const float* adjl = ADJ + 640 + slots[q] * 64;
        int M = BATCH * P.n;
        gemm256<true, false, false, false><<<M / 256, blk512, 0, stream>>>(
            Xb, Wat, nullptr, P1, M, 256, 512, 512, 256,
            P.n, P.idx[0], P.idx[1], P.idx[2], P.idx[3], P.idx[4], P.idx[5]);
        if (P.n == 5)
            mix_inplace<5><<<BATCH * 256 / 256, blk, 0, stream>>>(P1, adjl, ba, 256, 256);
        else if (P.n == 3)
            mix_inplace<3><<<BATCH * 256 / 256, blk, 0, stream>>>(P1, adjl, ba, 256, 256);
        else
            mix_inplace<6><<<BATCH * 256 / 256, blk, 0, stream>>>(P1, adjl, ba, 256, 256);
        gemm256<false, false, false, false><<<(M / 256) * 2, blk512, 0, stream>>>(
            P1, Wbt, nullptr, P3, M, 512, 256, 256, 512, 0, 0, 0, 0, 0, 0, 0);
        if (P.n == 5)
            mix_scatter<5><<<BATCH * 512 / 256, blk, 0, stream>>>(
                P3, adjl, bb, XGL + 512, P.idx[0], P.idx[1], P.idx[2], P.idx[3], P.idx[4], P.idx[5]);
        else if (P.n == 3)
            mix_scatter<3><<<BATCH * 512 / 256, blk, 0, stream>>>(
                P3, adjl, bb, XGL + 512, P.idx[0], P.idx[1], P.idx[2], P.idx[3], P.idx[4], P.idx[5]);
        else
            mix_scatter<6><<<BATCH * 512 / 256, blk, 0, stream>>>(
                P3, adjl, bb, XGL + 512, P.idx[0], P.idx[1], P.idx[2], P.idx[3], P.idx[4], P.idx[5]);
    }

    // fusion: HF = relu(XGL @ Wf0 + bf0) ; out = HF @ Wf1 + bf1 (fp32 out)
    gemm256<false, true, true, false><<<800, blk512, 0, stream>>>(
        XGL, Wf0t, bf0, HF, MROWS, 512, 1024, 1024, 512, 0, 0, 0, 0, 0, 0, 0);
    gemm256<false, true, false, true><<<800, blk512, 0, stream>>>(
        HF, Wf1t, bf1, (float*)d_out, MROWS, 512, 512, 512, 512, 0, 0, 0, 0, 0, 0, 0);

    (void)in_sizes; (void)n_in; (void)out_size; (void)ws_size;
}

// Round 2
// 1030.659 us; speedup vs baseline: 1.0850x; 1.0237x over previous
//
#include <hip/hip_runtime.h>

// ---------------------------------------------------------------------------
// GLA_GCN bf16-MFMA pipeline. B=4096, J=25, D_IN=512, D_H=256, D_OUT=512.
// Partition 1 is dead (all its joints overwritten by parts 2/3/4).
// GEMM: 256x256 tile, BK=64, 8 waves (2Mx4N), 8-phase schedule (m201
// template): per phase {ds_read subtile + stage 1 half-tile -> barrier ->
// lgkmcnt(0) -> setprio(1) 16xMFMA setprio(0) -> barrier}, counted vmcnt(4)
// at P3/P7 only (never 0 mid-loop), 2dbuf x 4 half-tile LDS (128 KiB),
// chunk-XOR swizzle (conflict-free ds_read_b128), XCD block swizzle.
// XG|XL stored interleaved per row (XGL, lda=1024) so fusion GEMM is plain.
// ---------------------------------------------------------------------------

#define BATCH 4096
#define NJOINT 25
#define MROWS (BATCH * NJOINT)          // 102400
#define SZ_FULL (MROWS * 512)           // 52,428,800 bf16 elements

typedef __attribute__((ext_vector_type(8))) short short8;
typedef __attribute__((ext_vector_type(4))) float float4_;

__device__ __forceinline__ float b2f(ushort u) {
    union { float f; uint32_t i; } x; x.i = ((uint32_t)u) << 16; return x.f;
}
__device__ __forceinline__ ushort f2b(float f) {
    union { float f; uint32_t i; } x; x.f = f;
    uint32_t r = x.i + 0x7fff + ((x.i >> 16) & 1);
    return (ushort)(r >> 16);
}
__device__ __forceinline__ void async16(const void* g, void* l) {
    __builtin_amdgcn_global_load_lds(
        (const __attribute__((address_space(1))) void*)g,
        (__attribute__((address_space(3))) void*)l, 16, 0, 0);
}

// ---------------------------------------------------------------------------
// Adjacency normalization (fp32, tiny)
// ---------------------------------------------------------------------------
__device__ void norm_one(const float* A, int n, float* out, float* sAdj, float* sD) {
    int t = threadIdx.x;
    for (int i = t; i < n * n; i += 256) sAdj[i] = A[i];
    __syncthreads();
    if (t < n) {
        float s = 0.f;
        for (int j = 0; j < n; j++) s += sAdj[t * n + j];
        sD[t] = 1.0f / sqrtf(fmaxf(s, 1e-6f));
    }
    __syncthreads();
    for (int i = t; i < n * n; i += 256) {
        int r = i / n, c = i % n;
        out[i] = sD[r] * sAdj[i] * sD[c];
    }
    __syncthreads();
}

__global__ __launch_bounds__(256) void adjnorm_kernel(
    const float* Ag, const float* A0, const float* A2, const float* A3,
    const float* A4, float* ADJ) {
    __shared__ float sAdj[640];
    __shared__ float sD[32];
    norm_one(Ag, 25, ADJ, sAdj, sD);
    norm_one(A0, 5, ADJ + 640 + 0 * 64, sAdj, sD);
    norm_one(A2, 3, ADJ + 640 + 1 * 64, sAdj, sD);
    norm_one(A3, 3, ADJ + 640 + 2 * 64, sAdj, sD);
    norm_one(A4, 6, ADJ + 640 + 3 * 64, sAdj, sD);
}

// ---------------------------------------------------------------------------
// fp32 -> bf16 convert (x), float4 -> ushort4
// ---------------------------------------------------------------------------
__global__ __launch_bounds__(256) void cvt_bf16(const float* __restrict__ in,
                                                ushort* __restrict__ out, int n4) {
    int id = blockIdx.x * 256 + threadIdx.x;
    if (id < n4) {
        float4 v = ((const float4*)in)[id];
        ushort4 o;
        o.x = f2b(v.x); o.y = f2b(v.y); o.z = f2b(v.z); o.w = f2b(v.w);
        ((ushort4*)out)[id] = o;
    }
}

// ---------------------------------------------------------------------------
// Weight transpose + convert: W fp32 [K][N] -> Wt bf16 [N][K]. K,N mult of 32.
// ---------------------------------------------------------------------------
__global__ __launch_bounds__(256) void wtrans(const float* __restrict__ W,
                                              ushort* __restrict__ Wt, int K, int N) {
    __shared__ float tile[32][33];
    int t = threadIdx.x;
    int tx = t & 31, ty = t >> 5;  // ty 0..7
    int k0 = blockIdx.y * 32, n0 = blockIdx.x * 32;
    for (int r = ty; r < 32; r += 8)
        tile[r][tx] = W[(size_t)(k0 + r) * N + n0 + tx];
    __syncthreads();
    for (int r = ty; r < 32; r += 8)
        Wt[(size_t)(n0 + r) * K + k0 + tx] = f2b(tile[tx][r]);
}

// ---------------------------------------------------------------------------
// Zero XL joints 17..24 in XGL interleaved layout (row stride 1024, XL at +512)
// ---------------------------------------------------------------------------
__global__ __launch_bounds__(256) void zero_tail(ushort* __restrict__ XGL) {
    int id = blockIdx.x * 256 + threadIdx.x;   // 4,194,304 ushort4 writes
    int f4 = id & 127;
    int rj = (id >> 7) & 7;
    int b = id >> 10;
    ushort4 z; z.x = 0; z.y = 0; z.z = 0; z.w = 0;
    ((ushort4*)(XGL + ((size_t)(b * 25 + 17 + rj) * 1024 + 512)))[f4] = z;
}

// ---------------------------------------------------------------------------
// bf16 MFMA GEMM, 8-phase schedule.
//   C[M,N] = act(A @ Wt^T + bias); A row-major (lda), Wt [N][K], C (ldc).
//   256x256 tile, BK=64, 8 waves (2Mx4N), per-wave 128x64 via 8x4x2 of
//   mfma_f32_16x16x32_bf16. LDS: 2 dbuf x {A0,A1,B0,B1} half-tiles of
//   16 KiB = 128 KiB. One iteration = 2 K-tiles = 8 phases; each phase
//   computes one fi-pair (16 MFMA) and stages one half-tile.
//   Stage stream (iter j): P0/P1: kt(2j+1).A0/A1 -> dbuf1; P2/P3:
//   kt(2j+2).B0/B1 -> dbuf0; P4/P5: kt(2j+2).A0/A1 -> dbuf0; P6/P7:
//   kt(2j+3).B0/B1 -> dbuf1. vmcnt(4) at P3 (covers dbuf1 for P4..P7)
//   and P7 (covers dbuf0 for next P0..P3); each wait is barrier-separated
//   from the first read of the data it covers, so cross-wave safety is
//   transitive through the phase barriers. Swizzle: LDS rows are 8 chunks
//   of 16B; linear LDS dest, source chunk = lane_chunk ^ (row&7), read
//   chunk = (kk*4+q) ^ (lr&7)  => <=2-way bank aliasing (free).
//   GATHER: A row m -> Xb row (m/gn)*25 + idx[m%gn] (staging only).
// ---------------------------------------------------------------------------
template <bool GATHER, bool BIAS, bool RELU, bool OUTF32>
__global__ __launch_bounds__(512, 2) void gemm256(
    const ushort* __restrict__ A, const ushort* __restrict__ Wt,
    const float* __restrict__ bias, void* __restrict__ C,
    int M, int N, int K, int lda, int ldc,
    int gn, int g0, int g1, int g2, int g3, int g4, int g5) {
    __shared__ ushort lds[65536];   // 128 KiB: [2 dbuf][4 slots][8192]
    int t = threadIdx.x;
    int l = t & 63, w = t >> 6;

    // bijective XCD swizzle (all grids are multiples of 8); N-tile fastest
    int nwg = (int)gridDim.x;
    int cpx = nwg >> 3;
    int wg = ((int)blockIdx.x & 7) * cpx + ((int)blockIdx.x >> 3);
    int gx = N >> 8;
    int tm = wg / gx, tn = wg - tm * gx;
    int bm = tm << 8, bn = tn << 8;

    // ---- staging pointers: lane l covers row (l>>3), linear chunk (l&7);
    //      source chunk pre-swizzled by ^(row&7) = ^(l>>3) ----
    int srow = (w << 4) + (l >> 3);
    int sch = ((l & 7) ^ (l >> 3)) << 3;         // element offset
    const ushort* pA[2][2];
    const ushort* pB[2][2];
    {
        int map_[6] = {g0, g1, g2, g3, g4, g5};
#pragma unroll
        for (int h = 0; h < 2; h++)
#pragma unroll
            for (int i = 0; i < 2; i++) {
                int r = bm + h * 128 + srow + i * 8;
                if (GATHER) { int b = r / gn; r = b * 25 + map_[r - b * gn]; }
                pA[h][i] = A + (size_t)r * lda + sch;
                int c = bn + h * 128 + srow + i * 8;
                pB[h][i] = Wt + (size_t)c * K + sch;
            }
    }
    int stga = w << 10;                           // (w*16 rows)*64 ushorts

    // ---- fragment read offsets ----
    int wm = w >> 2, wn = w & 3;                  // 2 x 4 wave grid
    int lr = l & 15, q = l >> 4;
    int cx = lr & 7;
    int ca0 = (q ^ cx) << 3;                      // kk=0 chunk
    int ca1 = ca0 ^ 32;                           // kk=1 chunk (^4 chunks)
    int ra = (wm << 13) + (lr << 6);              // A slot base + row
    int rb = 16384 + ((wn >> 1) << 13) + ((wn & 1) << 12) + (lr << 6);

    float4_ acc[8][4];
#pragma unroll
    for (int fi = 0; fi < 8; fi++)
#pragma unroll
        for (int fj = 0; fj < 4; fj++) acc[fi][fj] = (float4_)0.f;
    short8 bfr[4][2];

#define STG_A(DB, H, KT) do {                                              \
        async16(pA[H][0] + (KT) * 64, &lds[(DB) + (H) * 8192 + stga]);     \
        async16(pA[H][1] + (KT) * 64, &lds[(DB) + (H) * 8192 + stga + 512]); \
    } while (0)
#define STG_B(DB, H, KT) do {                                              \
        async16(pB[H][0] + (KT) * 64, &lds[(DB) + 16384 + (H) * 8192 + stga]); \
        async16(pB[H][1] + (KT) * 64, &lds[(DB) + 16384 + (H) * 8192 + stga + 512]); \
    } while (0)

#define DO_PHASE(DB, FI0, RDB, WAITST, ...) do {                           \
        short8 af00, af01, af10, af11;                                     \
        if (RDB) {                                                         \
            _Pragma("unroll")                                              \
            for (int fj = 0; fj < 4; fj++) {                               \
                bfr[fj][0] = *(const short8*)&lds[(DB) + rb + fj * 1024 + ca0]; \
                bfr[fj][1] = *(const short8*)&lds[(DB) + rb + fj * 1024 + ca1]; \
            }                                                              \
        }                                                                  \
        af00 = *(const short8*)&lds[(DB) + ra + (FI0) * 1024 + ca0];       \
        af01 = *(const short8*)&lds[(DB) + ra + (FI0) * 1024 + ca1];       \
        af10 = *(const short8*)&lds[(DB) + ra + ((FI0) + 1) * 1024 + ca0]; \
        af11 = *(const short8*)&lds[(DB) + ra + ((FI0) + 1) * 1024 + ca1]; \
        __VA_ARGS__                                                        \
        WAITST                                                             \
        if (RDB) asm volatile("s_waitcnt lgkmcnt(8)");                     \
        __builtin_amdgcn_sched_barrier(0);                                 \
        __builtin_amdgcn_s_barrier();                                      \
        asm volatile("s_waitcnt lgkmcnt(0)" ::: "memory");                 \
        __builtin_amdgcn_sched_barrier(0);                                 \
        __builtin_amdgcn_s_setprio(1);                                     \
        _Pragma("unroll")                                                  \
        for (int fj = 0; fj < 4; fj++) {                                   \
            acc[FI0][fj] = __builtin_amdgcn_mfma_f32_16x16x32_bf16(        \
                af00, bfr[fj][0], acc[FI0][fj], 0, 0, 0);                  \
            acc[FI0][fj] = __builtin_amdgcn_mfma_f32_16x16x32_bf16(        \
                af01, bfr[fj][1], acc[FI0][fj], 0, 0, 0);                  \
            acc[(FI0) + 1][fj] = __builtin_amdgcn_mfma_f32_16x16x32_bf16(  \
                af10, bfr[fj][0], acc[(FI0) + 1][fj], 0, 0, 0);            \
            acc[(FI0) + 1][fj] = __builtin_amdgcn_mfma_f32_16x16x32_bf16(  \
                af11, bfr[fj][1], acc[(FI0) + 1][fj], 0, 0, 0);            \
        }                                                                  \
        __builtin_amdgcn_s_setprio(0);                                     \
        __builtin_amdgcn_sched_barrier(0);                                 \
        __builtin_amdgcn_s_barrier();                                      \
    } while (0)

    int NT = K >> 6;              // K-tiles of 64 (NT even, >= 2)
    int NITER = NT >> 1;

    // prologue: kt0 complete + kt1.B; wait for kt0, barrier.
    STG_A(0, 0, 0); STG_A(0, 1, 0);
    STG_B(0, 0, 0); STG_B(0, 1, 0);
    STG_B(32768, 0, 1); STG_B(32768, 1, 1);
    asm volatile("s_waitcnt vmcnt(4)" ::: "memory");
    __builtin_amdgcn_sched_barrier(0);
    __builtin_amdgcn_s_barrier();

    for (int j = 0; j < NITER; ++j) {
        int k1 = 2 * j + 1, k2 = 2 * j + 2, k3 = 2 * j + 3;
        bool nl = (j + 1 < NITER);
        DO_PHASE(0, 0, true, , STG_A(32768, 0, k1););
        DO_PHASE(0, 2, false, , STG_A(32768, 1, k1););
        DO_PHASE(0, 4, false, , if (nl) STG_B(0, 0, k2););
        DO_PHASE(0, 6, false,
                 if (nl) { asm volatile("s_waitcnt vmcnt(4)" ::: "memory"); }
                 else    { asm volatile("s_waitcnt vmcnt(0)" ::: "memory"); },
                 if (nl) STG_B(0, 1, k2););
        DO_PHASE(32768, 0, true, , if (nl) STG_A(0, 0, k2););
        DO_PHASE(32768, 2, false, , if (nl) STG_A(0, 1, k2););
        DO_PHASE(32768, 4, false, , if (nl) STG_B(32768, 0, k3););
        DO_PHASE(32768, 6, false,
                 if (nl) { asm volatile("s_waitcnt vmcnt(4)" ::: "memory"); },
                 if (nl) STG_B(32768, 1, k3););
    }
#undef DO_PHASE
#undef STG_A
#undef STG_B

    // epilogue: C/D layout col=lane&15, row=(lane>>4)*4+reg
    int cl = lr;
    float bv[4];
#pragma unroll
    for (int fj = 0; fj < 4; fj++)
        bv[fj] = BIAS ? bias[bn + (wn << 6) + (fj << 4) + cl] : 0.f;
#pragma unroll
    for (int fi = 0; fi < 8; fi++) {
        int row0 = bm + (wm << 7) + (fi << 4) + (q << 2);
#pragma unroll
        for (int r = 0; r < 4; r++) {
            size_t rowoff = (size_t)(row0 + r) * ldc;
#pragma unroll
            for (int fj = 0; fj < 4; fj++) {
                int col = bn + (wn << 6) + (fj << 4) + cl;
                float v = acc[fi][fj][r] + bv[fj];
                if (RELU) v = fmaxf(v, 0.f);
                if (OUTF32)
                    ((float*)C)[rowoff + col] = v;
                else
                    ((ushort*)C)[rowoff + col] = f2b(v);
            }
        }
    }
    (void)M;
}

// ---------------------------------------------------------------------------
// In-place joint mix on bf16 tensor with row stride ldr:
//   T[b,i,f] = relu(sum_j adj[i,j]*T[b,j,f] + bias[f])
// ---------------------------------------------------------------------------
template <int NJ>
__global__ __launch_bounds__(256) void mix_inplace(
    ushort* __restrict__ T, const float* __restrict__ adjn,
    const float* __restrict__ bias, int F, int ldr) {
    __shared__ float As[NJ * NJ];
    int t = threadIdx.x;
    for (int i = t; i < NJ * NJ; i += 256) As[i] = adjn[i];
    __syncthreads();
    int id = blockIdx.x * 256 + t;
    int f = id % F;
    int b = id / F;
    ushort* base = T + (size_t)(b * NJ) * ldr + f;
    float v[NJ];
#pragma unroll
    for (int j = 0; j < NJ; j++) v[j] = b2f(base[(size_t)j * ldr]);
    float bi = bias[f];
#pragma unroll
    for (int i = 0; i < NJ; i++) {
        float o = 0.f;
#pragma unroll
        for (int j = 0; j < NJ; j++) o += As[i * NJ + j] * v[j];
        base[(size_t)i * ldr] = f2b(fmaxf(o + bi, 0.f));
    }
}

// ---------------------------------------------------------------------------
// Local layer-b mix + scatter into XL half of XGL (row stride 1024), bf16
// ---------------------------------------------------------------------------
template <int NJ>
__global__ __launch_bounds__(256) void mix_scatter(
    const ushort* __restrict__ P, const float* __restrict__ adjn,
    const float* __restrict__ bias, ushort* __restrict__ XL,
    int j0, int j1, int j2, int j3, int j4, int j5) {
    __shared__ float As[NJ * NJ];
    __shared__ int jm[NJ];
    int t = threadIdx.x;
    for (int i = t; i < NJ * NJ; i += 256) As[i] = adjn[i];
    if (t == 0) {
        int tmp[6] = {j0, j1, j2, j3, j4, j5};
        for (int i = 0; i < NJ; i++) jm[i] = tmp[i];
    }
    __syncthreads();
    int id = blockIdx.x * 256 + t;
    int f = id & 511;
    int b = id >> 9;
    float v[NJ];
    const ushort* base = P + (size_t)(b * NJ) * 512 + f;
#pragma unroll
    for (int j = 0; j < NJ; j++) v[j] = b2f(base[(size_t)j * 512]);
    float bi = bias[f];
#pragma unroll
    for (int i = 0; i < NJ; i++) {
        float o = 0.f;
#pragma unroll
        for (int j = 0; j < NJ; j++) o += As[i * NJ + j] * v[j];
        XL[((size_t)(b * 25 + jm[i])) * 1024 + f] = f2b(fmaxf(o + bi, 0.f));
    }
}

// ---------------------------------------------------------------------------
extern "C" void kernel_launch(void* const* d_in, const int* in_sizes, int n_in,
                              void* d_out, int out_size, void* d_ws,
                              size_t ws_size, hipStream_t stream) {
    const float* x    = (const float*)d_in[0];
    const float* adjg = (const float*)d_in[1];
    const float* al0  = (const float*)d_in[2];
    const float* al2  = (const float*)d_in[4];
    const float* al3  = (const float*)d_in[5];
    const float* al4  = (const float*)d_in[6];
    const float* Wg0  = (const float*)d_in[7];
    const float* bg0  = (const float*)d_in[8];
    const float* Wg1  = (const float*)d_in[9];
    const float* bg1  = (const float*)d_in[10];
    const float* Wf0  = (const float*)d_in[31];
    const float* bf0  = (const float*)d_in[32];
    const float* Wf1  = (const float*)d_in[33];
    const float* bf1  = (const float*)d_in[34];

    float* ws = (float*)d_ws;
    float* ADJ = ws;                          // 4096 floats
    ushort* U  = (ushort*)(ws + 4096);
    ushort* Xb  = U;                          // (B*25,512) bf16; HF reuses this
    ushort* XGL = U + (size_t)SZ_FULL;        // (B*25,1024): [XG | XL] per row
    ushort* S   = XGL + (size_t)MROWS * 1024; // 26.2M ushorts scratch
    ushort* T  = S;                           // (B*25,256)
    ushort* P1 = S;                           // (B*n,256) <= 6.3M
    ushort* P3 = S + 6291456;                 // (B*n,512) <= 12.6M
    ushort* Wb = S + 26214400;                // 2.1M ushorts of weights
    ushort* HF = Xb;                          // fusion hidden, reuses Xb

    ushort* Wg0t = Wb;                        // [256][512]
    ushort* Wg1t = Wb + 131072;               // [512][256]
    ushort* Wf0t = Wb + 1310720;              // [512][1024]
    ushort* Wf1t = Wb + 1835008;              // [512][512]

    dim3 blk(256);
    dim3 blk512(512);

    adjnorm_kernel<<<1, blk, 0, stream>>>(adjg, al0, al2, al3, al4, ADJ);
    cvt_bf16<<<SZ_FULL / 4 / 256, blk, 0, stream>>>(x, Xb, SZ_FULL / 4);
    zero_tail<<<16384, blk, 0, stream>>>(XGL);

    wtrans<<<dim3(256 / 32, 512 / 32), blk, 0, stream>>>(Wg0, Wg0t, 512, 256);
    wtrans<<<dim3(512 / 32, 256 / 32), blk, 0, stream>>>(Wg1, Wg1t, 256, 512);
    wtrans<<<dim3(512 / 32, 1024 / 32), blk, 0, stream>>>(Wf0, Wf0t, 1024, 512);
    wtrans<<<dim3(512 / 32, 512 / 32), blk, 0, stream>>>(Wf1, Wf1t, 512, 512);

    struct Part { int n, widx; int idx[6]; };
    const Part parts[4] = {
        {5, 11, {0, 1, 2, 3, 4, 0}},
        {3, 19, {5, 7, 9, 0, 0, 0}},
        {3, 23, {6, 8, 10, 0, 0, 0}},
        {6, 27, {11, 12, 13, 14, 15, 16}},
    };
    for (int q = 0; q < 4; q++) {
        ushort* Wat = Wb + 262144 + q * 262144;
        ushort* Wbt = Wat + 131072;
        wtrans<<<dim3(8, 16), blk, 0, stream>>>((const float*)d_in[parts[q].widx], Wat, 512, 256);
        wtrans<<<dim3(16, 8), blk, 0, stream>>>((const float*)d_in[parts[q].widx + 2], Wbt, 256, 512);
    }

    // global branch: XG written into even half of XGL (ldc=1024)
    gemm256<false, false, false, false><<<400, blk512, 0, stream>>>(
        Xb, Wg0t, nullptr, T, MROWS, 256, 512, 512, 256, 0, 0, 0, 0, 0, 0, 0);
    mix_inplace<25><<<BATCH * 256 / 256, blk, 0, stream>>>(T, ADJ, bg0, 256, 256);
    gemm256<false, false, false, false><<<800, blk512, 0, stream>>>(
        T, Wg1t, nullptr, XGL, MROWS, 512, 256, 256, 1024, 0, 0, 0, 0, 0, 0, 0);
    mix_inplace<25><<<BATCH * 512 / 256, blk, 0, stream>>>(XGL, ADJ, bg1, 512, 1024);

    // local branch (parts 0,2,3,4); XL written into odd half of XGL
    const int slots[4] = {0, 1, 2, 3};
    for (int q = 0; q < 4; q++) {
        const Part& P = parts[q];
        const float* ba = (const float*)d_in[P.widx + 1];
        const float* bb = (const float*)d_in[P.widx + 3];
        ushort* Wat = Wb + 262144 + q * 262144;
        ushort* Wbt = Wat + 131072;
        const float* adjl = ADJ + 640 + slots[q] * 64;
        int M = BATCH * P.n;
        gemm256<true, false, false, false><<<M / 256, blk512, 0, stream>>>(
            Xb, Wat, nullptr, P1, M, 256, 512, 512, 256,
            P.n, P.idx[0], P.idx[1], P.idx[2], P.idx[3], P.idx[4], P.idx[5]);
        if (P.n == 5)
            mix_inplace<5><<<BATCH * 256 / 256, blk, 0, stream>>>(P1, adjl, ba, 256, 256);
        else if (P.n == 3)
            mix_inplace<3><<<BATCH * 256 / 256, blk, 0, stream>>>(P1, adjl, ba, 256, 256);
        else
            mix_inplace<6><<<BATCH * 256 / 256, blk, 0, stream>>>(P1, adjl, ba, 256, 256);
        gemm256<false, false, false, false><<<(M / 256) * 2, blk512, 0, stream>>>(
            P1, Wbt, nullptr, P3, M, 512, 256, 256, 512, 0, 0, 0, 0, 0, 0, 0);
        if (P.n == 5)
            mix_scatter<5><<<BATCH * 512 / 256, blk, 0, stream>>>(
                P3, adjl, bb, XGL + 512, P.idx[0], P.idx[1], P.idx[2], P.idx[3], P.idx[4], P.idx[5]);
        else if (P.n == 3)
            mix_scatter<3><<<BATCH * 512 / 256, blk, 0, stream>>>(
                P3, adjl, bb, XGL + 512, P.idx[0], P.idx[1], P.idx[2], P.idx[3], P.idx[4], P.idx[5]);
        else
            mix_scatter<6><<<BATCH * 512 / 256, blk, 0, stream>>>(
                P3, adjl, bb, XGL + 512, P.idx[0], P.idx[1], P.idx[2], P.idx[3], P.idx[4], P.idx[5]);
    }

    // fusion: HF = relu(XGL @ Wf0 + bf0) ; out = HF @ Wf1 + bf1 (fp32 out)
    gemm256<false, true, true, false><<<800, blk512, 0, stream>>>(
        XGL, Wf0t, bf0, HF, MROWS, 512, 1024, 1024, 512, 0, 0, 0, 0, 0, 0, 0);
    gemm256<false, true, false, true><<<800, blk512, 0, stream>>>(
        HF, Wf1t, bf1, (float*)d_out, MROWS, 512, 512, 512, 512, 0, 0, 0, 0, 0, 0, 0);

    (void)in_sizes; (void)n_in; (void)out_size; (void)ws_size;
}

// Round 3
// 963.902 us; speedup vs baseline: 1.1602x; 1.0693x over previous
//
#include <hip/hip_runtime.h>

// ---------------------------------------------------------------------------
// GLA_GCN bf16-MFMA pipeline. B=4096, J=25, D_IN=512, D_H=256, D_OUT=512.
// Partition 1 is dead (all its joints overwritten by parts 2/3/4).
// GEMMs are GROUPED: one dispatch for all five "a" GEMMs (global+4 parts,
// 672 wg), one for all five "b" GEMMs (1344 wg), plus Wf0/Wf1 (800 wg each).
// GEMM inner loop: 256x256 tile, BK=64, 8 waves, 8-phase schedule with
// counted vmcnt(4) at P3/P7 (never 0 mid-loop), 2dbuf x 4 half-tile LDS
// (128 KiB), chunk-XOR swizzle (bank-conflict-free ds_read_b128), setprio
// around MFMA, XCD block swizzle. Sync uses raw s_barrier + compiler-only
// memory fences (no sched_barrier pinning, no hard lgkmcnt(0)): compiler
// emits fine-grained lgkmcnt(N) per MFMA operand.
// XG|XL stored interleaved per row (XGL, lda=1024) so fusion GEMM is plain.
// ---------------------------------------------------------------------------

#define BATCH 4096
#define NJOINT 25
#define MROWS (BATCH * NJOINT)          // 102400
#define SZ_FULL (MROWS * 512)           // 52,428,800 bf16 elements

typedef __attribute__((ext_vector_type(8))) short short8;
typedef __attribute__((ext_vector_type(4))) float float4_;

__device__ __forceinline__ float b2f(ushort u) {
    union { float f; uint32_t i; } x; x.i = ((uint32_t)u) << 16; return x.f;
}
__device__ __forceinline__ ushort f2b(float f) {
    union { float f; uint32_t i; } x; x.f = f;
    uint32_t r = x.i + 0x7fff + ((x.i >> 16) & 1);
    return (ushort)(r >> 16);
}
__device__ __forceinline__ void async16(const void* g, void* l) {
    __builtin_amdgcn_global_load_lds(
        (const __attribute__((address_space(1))) void*)g,
        (__attribute__((address_space(3))) void*)l, 16, 0, 0);
}

// ---------------------------------------------------------------------------
// Adjacency normalization (fp32, tiny)
// ---------------------------------------------------------------------------
__device__ void norm_one(const float* A, int n, float* out, float* sAdj, float* sD) {
    int t = threadIdx.x;
    for (int i = t; i < n * n; i += 256) sAdj[i] = A[i];
    __syncthreads();
    if (t < n) {
        float s = 0.f;
        for (int j = 0; j < n; j++) s += sAdj[t * n + j];
        sD[t] = 1.0f / sqrtf(fmaxf(s, 1e-6f));
    }
    __syncthreads();
    for (int i = t; i < n * n; i += 256) {
        int r = i / n, c = i % n;
        out[i] = sD[r] * sAdj[i] * sD[c];
    }
    __syncthreads();
}

__global__ __launch_bounds__(256) void adjnorm_kernel(
    const float* Ag, const float* A0, const float* A2, const float* A3,
    const float* A4, float* ADJ) {
    __shared__ float sAdj[640];
    __shared__ float sD[32];
    norm_one(Ag, 25, ADJ, sAdj, sD);
    norm_one(A0, 5, ADJ + 640 + 0 * 64, sAdj, sD);
    norm_one(A2, 3, ADJ + 640 + 1 * 64, sAdj, sD);
    norm_one(A3, 3, ADJ + 640 + 2 * 64, sAdj, sD);
    norm_one(A4, 6, ADJ + 640 + 3 * 64, sAdj, sD);
}

// ---------------------------------------------------------------------------
// fp32 -> bf16 convert (x), float4 -> ushort4
// ---------------------------------------------------------------------------
__global__ __launch_bounds__(256) void cvt_bf16(const float* __restrict__ in,
                                                ushort* __restrict__ out, int n4) {
    int id = blockIdx.x * 256 + threadIdx.x;
    if (id < n4) {
        float4 v = ((const float4*)in)[id];
        ushort4 o;
        o.x = f2b(v.x); o.y = f2b(v.y); o.z = f2b(v.z); o.w = f2b(v.w);
        ((ushort4*)out)[id] = o;
    }
}

// ---------------------------------------------------------------------------
// Grouped weight transpose: W fp32 [K][N] -> Wt bf16 [N][K], 12 regions.
// ---------------------------------------------------------------------------
struct WDesc { const float* W; ushort* Wt; int K, N, nxlog, end; };
struct WParams { WDesc d[12]; };

__global__ __launch_bounds__(256) void wtrans_all(WParams P) {
    __shared__ float tile[32][33];
    int bid = blockIdx.x;
    int i = 0, start = 0;
    while (bid >= P.d[i].end) { start = P.d[i].end; i++; }
    const WDesc& D = P.d[i];
    int local = bid - start;
    int bx = local & ((1 << D.nxlog) - 1);
    int by = local >> D.nxlog;
    int K = D.K, N = D.N;
    int t = threadIdx.x, tx = t & 31, ty = t >> 5;
    int k0 = by * 32, n0 = bx * 32;
    for (int r = ty; r < 32; r += 8)
        tile[r][tx] = D.W[(size_t)(k0 + r) * N + n0 + tx];
    __syncthreads();
    for (int r = ty; r < 32; r += 8)
        D.Wt[(size_t)(n0 + r) * K + k0 + tx] = f2b(tile[tx][r]);
}

// ---------------------------------------------------------------------------
// Zero XL joints 17..24 in XGL interleaved layout (row stride 1024, XL at +512)
// ---------------------------------------------------------------------------
__global__ __launch_bounds__(256) void zero_tail(ushort* __restrict__ XGL) {
    int id = blockIdx.x * 256 + threadIdx.x;
    int f4 = id & 127;
    int rj = (id >> 7) & 7;
    int b = id >> 10;
    ushort4 z; z.x = 0; z.y = 0; z.z = 0; z.w = 0;
    ((ushort4*)(XGL + ((size_t)(b * 25 + 17 + rj) * 1024 + 512)))[f4] = z;
}

// ---------------------------------------------------------------------------
// Grouped bf16 MFMA GEMM, 8-phase schedule. Up to 5 groups per dispatch.
//   Per group: C[M,N] = act(A @ Wt^T [+ bias]); A row-major (lda),
//   Wt [N][K], C (ldc). flags: 1=GATHER, 2=BIAS, 4=RELU, 8=OUTF32.
//   256x256 tile, BK=64, 8 waves (2Mx4N), per-wave 128x64 via 8x4x2 of
//   mfma_f32_16x16x32_bf16. LDS: 2 dbuf x {A0,A1,B0,B1} 16 KiB half-tiles.
//   Stage stream (iter j): P0/P1 kt(2j+1).A -> dbuf1; P2/P3 kt(2j+2).B ->
//   dbuf0; P4/P5 kt(2j+2).A -> dbuf0; P6/P7 kt(2j+3).B -> dbuf1.
//   vmcnt(4) at P3 (covers dbuf1 for P4..P7) and P7 (covers dbuf0 for next
//   P0..P3); each wait is barrier-separated from the first read it covers.
//   Sync: s_barrier + empty "memory" asm (compiler fence only) -> loads and
//   stage-issues cannot cross a barrier at compile time, while the machine
//   schedule keeps compiler-derived fine-grained lgkmcnt per MFMA.
//   Swizzle: rows of 8 x 16B chunks; linear LDS dest, source chunk =
//   lanechunk ^ (row&7), read chunk = (q or q^4) ^ (row&7) => conflict-free.
// ---------------------------------------------------------------------------
struct GDesc {
    const ushort* A; const ushort* Wt; const float* bias; void* C;
    int K, lda, ldc, nTiles, wgEnd, gn, flags, pad;
    int gmap[6];
};
struct GParams { GDesc g[5]; };

__global__ __launch_bounds__(512, 2) void gemmg(GParams P) {
    __shared__ ushort lds[65536];   // 128 KiB: [2 dbuf][4 slots][8192]
    int t = threadIdx.x;
    int l = t & 63, w = t >> 6;

    // bijective XCD swizzle (all grids are multiples of 8)
    int nwg = (int)gridDim.x;
    int cpx = nwg >> 3;
    int wg = ((int)blockIdx.x & 7) * cpx + ((int)blockIdx.x >> 3);

    int gi = 0, wg0 = 0;
    while (wg >= P.g[gi].wgEnd) { wg0 = P.g[gi].wgEnd; gi++; }
    const GDesc& G = P.g[gi];
    int lw = wg - wg0;
    int tm, tn;
    if (G.nTiles == 2) { tm = lw >> 1; tn = lw & 1; }
    else               { tm = lw;      tn = 0; }
    int bm = tm << 8, bn = tn << 8;
    const int K = G.K, lda = G.lda, ldc = G.ldc;
    const bool GATHER = (G.flags & 1) != 0;
    const bool BIAS   = (G.flags & 2) != 0;
    const bool RELU   = (G.flags & 4) != 0;
    const bool OUTF32 = (G.flags & 8) != 0;

    // staging: lane l covers row (l>>3), linear chunk (l&7); source chunk
    // pre-swizzled by ^(row&7) = ^(l>>3)
    int srow = (w << 4) + (l >> 3);
    int sch = ((l & 7) ^ (l >> 3)) << 3;
    const ushort* pA[2][2];
    const ushort* pB[2][2];
#pragma unroll
    for (int h = 0; h < 2; h++)
#pragma unroll
        for (int i = 0; i < 2; i++) {
            int r = bm + h * 128 + srow + i * 8;
            if (GATHER) { int b = r / G.gn; r = b * 25 + G.gmap[r - b * G.gn]; }
            pA[h][i] = G.A + (size_t)r * lda + sch;
            int c = bn + h * 128 + srow + i * 8;
            pB[h][i] = G.Wt + (size_t)c * K + sch;
        }
    int stga = w << 10;

    // fragment read offsets
    int wm = w >> 2, wn = w & 3;
    int lr = l & 15, q = l >> 4;
    int cx = lr & 7;
    int ca0 = (q ^ cx) << 3;
    int ca1 = ca0 ^ 32;
    int ra = (wm << 13) + (lr << 6);
    int rb = 16384 + ((wn >> 1) << 13) + ((wn & 1) << 12) + (lr << 6);

    float4_ acc[8][4];
#pragma unroll
    for (int fi = 0; fi < 8; fi++)
#pragma unroll
        for (int fj = 0; fj < 4; fj++) acc[fi][fj] = (float4_)0.f;
    short8 bfr[4][2];

#define FENCE() asm volatile("" ::: "memory")
#define STG_A(DB, H, KT) do {                                              \
        async16(pA[H][0] + (KT) * 64, &lds[(DB) + (H) * 8192 + stga]);     \
        async16(pA[H][1] + (KT) * 64, &lds[(DB) + (H) * 8192 + stga + 512]); \
    } while (0)
#define STG_B(DB, H, KT) do {                                              \
        async16(pB[H][0] + (KT) * 64, &lds[(DB) + 16384 + (H) * 8192 + stga]); \
        async16(pB[H][1] + (KT) * 64, &lds[(DB) + 16384 + (H) * 8192 + stga + 512]); \
    } while (0)

#define DO_PHASE(DB, FI0, RDB, WAITST, STMT) do {                          \
        short8 af00, af01, af10, af11;                                     \
        if (RDB) {                                                         \
            _Pragma("unroll")                                              \
            for (int fj = 0; fj < 4; fj++) {                               \
                bfr[fj][0] = *(const short8*)&lds[(DB) + rb + fj * 1024 + ca0]; \
                bfr[fj][1] = *(const short8*)&lds[(DB) + rb + fj * 1024 + ca1]; \
            }                                                              \
        }                                                                  \
        af00 = *(const short8*)&lds[(DB) + ra + (FI0) * 1024 + ca0];       \
        af01 = *(const short8*)&lds[(DB) + ra + (FI0) * 1024 + ca1];       \
        af10 = *(const short8*)&lds[(DB) + ra + ((FI0) + 1) * 1024 + ca0]; \
        af11 = *(const short8*)&lds[(DB) + ra + ((FI0) + 1) * 1024 + ca1]; \
        STMT                                                               \
        WAITST                                                             \
        __builtin_amdgcn_s_barrier();                                      \
        FENCE();                                                           \
        __builtin_amdgcn_s_setprio(1);                                     \
        _Pragma("unroll")                                                  \
        for (int fj = 0; fj < 4; fj++) {                                   \
            acc[FI0][fj] = __builtin_amdgcn_mfma_f32_16x16x32_bf16(        \
                af00, bfr[fj][0], acc[FI0][fj], 0, 0, 0);                  \
            acc[FI0][fj] = __builtin_amdgcn_mfma_f32_16x16x32_bf16(        \
                af01, bfr[fj][1], acc[FI0][fj], 0, 0, 0);                  \
            acc[(FI0) + 1][fj] = __builtin_amdgcn_mfma_f32_16x16x32_bf16(  \
                af10, bfr[fj][0], acc[(FI0) + 1][fj], 0, 0, 0);            \
            acc[(FI0) + 1][fj] = __builtin_amdgcn_mfma_f32_16x16x32_bf16(  \
                af11, bfr[fj][1], acc[(FI0) + 1][fj], 0, 0, 0);            \
        }                                                                  \
        __builtin_amdgcn_s_setprio(0);                                     \
        __builtin_amdgcn_s_barrier();                                      \
        FENCE();                                                           \
    } while (0)

    int NT = K >> 6;              // K-tiles of 64 (NT even, >= 4 here)
    int NITER = NT >> 1;

    // prologue: kt0 complete + kt1.B; wait for kt0, barrier.
    STG_A(0, 0, 0); STG_A(0, 1, 0);
    STG_B(0, 0, 0); STG_B(0, 1, 0);
    STG_B(32768, 0, 1); STG_B(32768, 1, 1);
    asm volatile("s_waitcnt vmcnt(4)" ::: "memory");
    __builtin_amdgcn_s_barrier();
    FENCE();

    for (int j = 0; j < NITER; ++j) {
        int k1 = 2 * j + 1, k2 = 2 * j + 2, k3 = 2 * j + 3;
        bool nl = (j + 1 < NITER);
        DO_PHASE(0, 0, true, , STG_A(32768, 0, k1););
        DO_PHASE(0, 2, false, , STG_A(32768, 1, k1););
        DO_PHASE(0, 4, false, , if (nl) STG_B(0, 0, k2););
        DO_PHASE(0, 6, false,
                 if (nl) { asm volatile("s_waitcnt vmcnt(4)" ::: "memory"); }
                 else    { asm volatile("s_waitcnt vmcnt(0)" ::: "memory"); },
                 if (nl) STG_B(0, 1, k2););
        DO_PHASE(32768, 0, true, , if (nl) STG_A(0, 0, k2););
        DO_PHASE(32768, 2, false, , if (nl) STG_A(0, 1, k2););
        DO_PHASE(32768, 4, false, , if (nl) STG_B(32768, 0, k3););
        DO_PHASE(32768, 6, false,
                 if (nl) { asm volatile("s_waitcnt vmcnt(4)" ::: "memory"); },
                 if (nl) STG_B(32768, 1, k3););
    }
#undef DO_PHASE
#undef STG_A
#undef STG_B
#undef FENCE

    // epilogue: C/D layout col=lane&15, row=(lane>>4)*4+reg
    int cl = lr;
    float bv[4];
#pragma unroll
    for (int fj = 0; fj < 4; fj++)
        bv[fj] = BIAS ? G.bias[bn + (wn << 6) + (fj << 4) + cl] : 0.f;
#pragma unroll
    for (int fi = 0; fi < 8; fi++) {
        int row0 = bm + (wm << 7) + (fi << 4) + (q << 2);
#pragma unroll
        for (int r = 0; r < 4; r++) {
            size_t rowoff = (size_t)(row0 + r) * ldc;
#pragma unroll
            for (int fj = 0; fj < 4; fj++) {
                int col = bn + (wn << 6) + (fj << 4) + cl;
                float v = acc[fi][fj][r] + bv[fj];
                if (RELU) v = fmaxf(v, 0.f);
                if (OUTF32)
                    ((float*)G.C)[rowoff + col] = v;
                else
                    ((ushort*)G.C)[rowoff + col] = f2b(v);
            }
        }
    }
}

// ---------------------------------------------------------------------------
// Grouped mix pass 1 (F=256): T[b,i,f] = relu(sum_j adj[i,j]*T[b,j,f]+bias[f])
// 5 regions x 4096 blocks.
// ---------------------------------------------------------------------------
struct M1Desc { ushort* T; const float* adj; const float* bias; int nj; };
struct M1Params { M1Desc d[5]; };

template <int NJ>
__device__ __forceinline__ void mix1_body(ushort* base, const float* As, float bi) {
    float v[NJ];
#pragma unroll
    for (int j = 0; j < NJ; j++) v[j] = b2f(base[(size_t)j * 256]);
#pragma unroll
    for (int i = 0; i < NJ; i++) {
        float o = 0.f;
#pragma unroll
        for (int j = 0; j < NJ; j++) o += As[i * NJ + j] * v[j];
        base[(size_t)i * 256] = f2b(fmaxf(o + bi, 0.f));
    }
}

__global__ __launch_bounds__(256) void mixg1(M1Params P) {
    __shared__ float As[625];
    int r = blockIdx.x >> 12;
    const M1Desc& D = P.d[r];
    int t = threadIdx.x;
    int nj = D.nj;
    for (int i = t; i < nj * nj; i += 256) As[i] = D.adj[i];
    __syncthreads();
    int id = ((blockIdx.x & 4095) << 8) + t;
    int f = id & 255, b = id >> 8;
    ushort* base = D.T + ((size_t)b * nj) * 256 + f;
    float bi = D.bias[f];
    switch (nj) {
        case 25: mix1_body<25>(base, As, bi); break;
        case 5:  mix1_body<5>(base, As, bi); break;
        case 3:  mix1_body<3>(base, As, bi); break;
        default: mix1_body<6>(base, As, bi); break;
    }
}

// ---------------------------------------------------------------------------
// Grouped mix pass 2 (F=512): scatter-form. Region 0: global in-place mix on
// XGL even half (sldr=1024, jm=identity). Regions 1-4: part mix P3 -> XGL
// odd half via joint map. 5 regions x 8192 blocks.
// ---------------------------------------------------------------------------
struct M2Desc {
    const ushort* src; ushort* dst; const float* adj; const float* bias;
    int nj, sldr; int jm[25];
};
struct M2Params { M2Desc d[5]; };

template <int NJ>
__device__ __forceinline__ void mix2_body(const ushort* src, int sldr, ushort* dst,
                                          const int* jms, const float* As, float bi) {
    float v[NJ];
#pragma unroll
    for (int j = 0; j < NJ; j++) v[j] = b2f(src[(size_t)j * sldr]);
#pragma unroll
    for (int i = 0; i < NJ; i++) {
        float o = 0.f;
#pragma unroll
        for (int j = 0; j < NJ; j++) o += As[i * NJ + j] * v[j];
        dst[(size_t)jms[i] * 1024] = f2b(fmaxf(o + bi, 0.f));
    }
}

__global__ __launch_bounds__(256) void mixg2(M2Params P) {
    __shared__ float As[625];
    __shared__ int jms[25];
    int r = blockIdx.x >> 13;
    const M2Desc& D = P.d[r];
    int t = threadIdx.x;
    int nj = D.nj;
    for (int i = t; i < nj * nj; i += 256) As[i] = D.adj[i];
    if (t < nj) jms[t] = D.jm[t];
    __syncthreads();
    int id = ((blockIdx.x & 8191) << 8) + t;
    int f = id & 511, b = id >> 9;
    const ushort* src = D.src + ((size_t)b * nj) * D.sldr + f;
    ushort* dst = D.dst + (size_t)b * 25 * 1024 + f;
    float bi = D.bias[f];
    switch (nj) {
        case 25: mix2_body<25>(src, D.sldr, dst, jms, As, bi); break;
        case 5:  mix2_body<5>(src, D.sldr, dst, jms, As, bi); break;
        case 3:  mix2_body<3>(src, D.sldr, dst, jms, As, bi); break;
        default: mix2_body<6>(src, D.sldr, dst, jms, As, bi); break;
    }
}

// ---------------------------------------------------------------------------
extern "C" void kernel_launch(void* const* d_in, const int* in_sizes, int n_in,
                              void* d_out, int out_size, void* d_ws,
                              size_t ws_size, hipStream_t stream) {
    const float* x    = (const float*)d_in[0];
    const float* adjg = (const float*)d_in[1];
    const float* al0  = (const float*)d_in[2];
    const float* al2  = (const float*)d_in[4];
    const float* al3  = (const float*)d_in[5];
    const float* al4  = (const float*)d_in[6];
    const float* Wg0  = (const float*)d_in[7];
    const float* bg0  = (const float*)d_in[8];
    const float* Wg1  = (const float*)d_in[9];
    const float* bg1  = (const float*)d_in[10];
    const float* Wf0  = (const float*)d_in[31];
    const float* bf0  = (const float*)d_in[32];
    const float* Wf1  = (const float*)d_in[33];
    const float* bf1  = (const float*)d_in[34];

    float* ws = (float*)d_ws;
    float* ADJ = ws;                               // 4096 floats
    ushort* U   = (ushort*)(ws + 4096);
    ushort* Xb  = U;                               // 52.4M (a-pass input)
    ushort* XGL = Xb + (size_t)SZ_FULL;            // 104.9M: [XG | XL] per row
    ushort* T   = XGL + (size_t)MROWS * 1024;      // 26.2M
    ushort* P1  = T + (size_t)MROWS * 256;         // 17.8M (B*17*256)
    ushort* Wb  = P1 + (size_t)BATCH * 17 * 256;   // 2.1M weights
    ushort* P3  = Xb;                              // 35.7M, reuses dead Xb
    ushort* HF  = Xb;                              // fusion hidden, reuses Xb

    ushort* Wg0t = Wb;                             // [256][512]
    ushort* Wg1t = Wb + 131072;                    // [512][256]
    ushort* Wf0t = Wb + 262144;                    // [512][1024]
    ushort* Wf1t = Wb + 786432;                    // [512][512]
    ushort* Wpt  = Wb + 1048576;                   // 4x (Wat 131072 + Wbt 131072)

    struct Part { int n, widx; int idx[6]; };
    const Part parts[4] = {
        {5, 11, {0, 1, 2, 3, 4, 0}},
        {3, 19, {5, 7, 9, 0, 0, 0}},
        {3, 23, {6, 8, 10, 0, 0, 0}},
        {6, 27, {11, 12, 13, 14, 15, 16}},
    };
    const int cumn[4] = {0, 5, 8, 11};

    dim3 blk(256), blk512(512);

    adjnorm_kernel<<<1, blk, 0, stream>>>(adjg, al0, al2, al3, al4, ADJ);
    cvt_bf16<<<SZ_FULL / 4 / 256, blk, 0, stream>>>(x, Xb, SZ_FULL / 4);
    zero_tail<<<16384, blk, 0, stream>>>(XGL);

    // grouped weight transposes (12 regions, 2048 blocks)
    {
        WParams WP{};
        int e = 0, i = 0;
        auto add = [&](const float* W, ushort* Wt, int K, int N) {
            int nx = N >> 5;
            int nxlog = (nx == 8) ? 3 : ((nx == 16) ? 4 : 5);
            e += nx * (K >> 5);
            WP.d[i++] = {W, Wt, K, N, nxlog, e};
        };
        add(Wg0, Wg0t, 512, 256);
        add(Wg1, Wg1t, 256, 512);
        add(Wf0, Wf0t, 1024, 512);
        add(Wf1, Wf1t, 512, 512);
        for (int qv = 0; qv < 4; qv++) {
            add((const float*)d_in[parts[qv].widx], Wpt + qv * 262144, 512, 256);
            add((const float*)d_in[parts[qv].widx + 2], Wpt + qv * 262144 + 131072, 256, 512);
        }
        wtrans_all<<<2048, blk, 0, stream>>>(WP);
    }

    auto setg = [](GDesc& g, const ushort* A, const ushort* Wt, const float* bias,
                   void* C, int K, int lda, int ldc, int nT, int wgEnd, int gn,
                   int flags, const int* map) {
        g.A = A; g.Wt = Wt; g.bias = bias; g.C = C; g.K = K; g.lda = lda;
        g.ldc = ldc; g.nTiles = nT; g.wgEnd = wgEnd; g.gn = gn; g.flags = flags;
        g.pad = 0;
        for (int i = 0; i < 6; i++) g.gmap[i] = map ? map[i] : 0;
    };

    // ---- a-pass: global (400 wg) + 4 local parts (272 wg) = 672 wg ----
    {
        GParams GA{};
        int e = 400;
        setg(GA.g[0], Xb, Wg0t, nullptr, T, 512, 512, 256, 1, e, 0, 0, nullptr);
        for (int qv = 0; qv < 4; qv++) {
            e += parts[qv].n * 16;
            setg(GA.g[1 + qv], Xb, Wpt + qv * 262144, nullptr,
                 P1 + (size_t)BATCH * cumn[qv] * 256,
                 512, 512, 256, 1, e, parts[qv].n, 1, parts[qv].idx);
        }
        gemmg<<<672, blk512, 0, stream>>>(GA);
    }

    // ---- mix pass 1 (F=256): global T + 4 parts P1 ----
    {
        M1Params M1{};
        M1.d[0] = {T, ADJ, bg0, 25};
        for (int qv = 0; qv < 4; qv++)
            M1.d[1 + qv] = {P1 + (size_t)BATCH * cumn[qv] * 256,
                            ADJ + 640 + qv * 64,
                            (const float*)d_in[parts[qv].widx + 1],
                            parts[qv].n};
        mixg1<<<20480, blk, 0, stream>>>(M1);
    }

    // ---- b-pass: global (800 wg) + 4 local parts (544 wg) = 1344 wg ----
    {
        GParams GB{};
        int e = 800;
        setg(GB.g[0], T, Wg1t, nullptr, XGL, 256, 256, 1024, 2, e, 0, 0, nullptr);
        for (int qv = 0; qv < 4; qv++) {
            e += parts[qv].n * 32;
            setg(GB.g[1 + qv], P1 + (size_t)BATCH * cumn[qv] * 256,
                 Wpt + qv * 262144 + 131072, nullptr,
                 P3 + (size_t)BATCH * cumn[qv] * 512,
                 256, 256, 512, 2, e, 0, 0, nullptr);
        }
        gemmg<<<1344, blk512, 0, stream>>>(GB);
    }

    // ---- mix pass 2 (F=512): global XGL in-place + 4 part scatters ----
    {
        M2Params M2{};
        M2.d[0].src = XGL; M2.d[0].dst = XGL; M2.d[0].adj = ADJ;
        M2.d[0].bias = bg1; M2.d[0].nj = 25; M2.d[0].sldr = 1024;
        for (int i = 0; i < 25; i++) M2.d[0].jm[i] = i;
        for (int qv = 0; qv < 4; qv++) {
            M2Desc& D = M2.d[1 + qv];
            D.src = P3 + (size_t)BATCH * cumn[qv] * 512;
            D.dst = XGL + 512;
            D.adj = ADJ + 640 + qv * 64;
            D.bias = (const float*)d_in[parts[qv].widx + 3];
            D.nj = parts[qv].n; D.sldr = 512;
            for (int i = 0; i < 25; i++) D.jm[i] = (i < 6) ? parts[qv].idx[i] : 0;
        }
        mixg2<<<40960, blk, 0, stream>>>(M2);
    }

    // ---- fusion: HF = relu(XGL @ Wf0 + bf0); out = HF @ Wf1 + bf1 (f32) ----
    {
        GParams GF{};
        setg(GF.g[0], XGL, Wf0t, bf0, HF, 1024, 1024, 512, 2, 800, 0, 2 | 4, nullptr);
        gemmg<<<800, blk512, 0, stream>>>(GF);
    }
    {
        GParams GO{};
        setg(GO.g[0], HF, Wf1t, bf1, d_out, 512, 512, 512, 2, 800, 0, 2 | 8, nullptr);
        gemmg<<<800, blk512, 0, stream>>>(GO);
    }

    (void)in_sizes; (void)n_in; (void)out_size; (void)ws_size;
}